// Round 1
// baseline (313.974 us; speedup 1.0000x reference)
//
#include <hip/hip_runtime.h>
#include <cstdint>
#include <cstddef>

typedef _Float16 f16;
typedef _Float16 f16x4 __attribute__((ext_vector_type(4)));
typedef _Float16 f16x8 __attribute__((ext_vector_type(8)));
typedef float    f32x4 __attribute__((ext_vector_type(4)));

#define NB 64
#define NN 262144   // 512*512

__device__ __forceinline__ void gload_lds16(const void* g, void* l) {
    __builtin_amdgcn_global_load_lds(
        (const __attribute__((address_space(1))) void*)g,
        (__attribute__((address_space(3))) void*)l, 16, 0, 0);
}

// r[b][n] = rsqrt(sum_i adj[b][i][n]) with 0 -> 0
__global__ void k_colsum(const float* __restrict__ adj, float* __restrict__ r) {
    int idx = blockIdx.x * 256 + threadIdx.x;      // 0..32767
    int b = idx >> 9, n = idx & 511;
    const float* col = adj + (size_t)b * NN + n;
    float s = 0.f;
    for (int i = 0; i < 512; ++i) s += col[(size_t)i * 512];
    r[idx] = (s > 0.f) ? rsqrtf(s) : 0.f;
}

// A_h[b][i][j] = f16( 16 * r[b][i] * adj[b][j][i] * r[b][j] )   (tiled transpose)
__global__ void k_makeA(const float* __restrict__ adj, const float* __restrict__ r,
                        f16* __restrict__ A_h) {
    __shared__ float t[64][65];
    int b = blockIdx.z;
    int i0 = blockIdx.y * 64, j0 = blockIdx.x * 64;
    const float* ab = adj + (size_t)b * NN;
    int c = threadIdx.x & 63, r4 = threadIdx.x >> 6;
    #pragma unroll
    for (int s = 0; s < 16; ++s) {
        int rr = r4 + s * 4;
        t[rr][c] = ab[(size_t)(j0 + rr) * 512 + i0 + c];   // adj[b][j0+rr][i0+c]
    }
    __syncthreads();
    const float* rb = r + (size_t)b * 512;
    f16* Ab = A_h + (size_t)b * NN;
    #pragma unroll
    for (int s = 0; s < 16; ++s) {
        int ii = r4 + s * 4;
        float v = 16.f * rb[i0 + ii] * t[c][ii] * rb[j0 + c];
        Ab[(size_t)(i0 + ii) * 512 + j0 + c] = (f16)v;
    }
}

// Wt[d][k] = f16( 64 * W[k][d] )
__global__ void k_transW(const float* __restrict__ W, f16* __restrict__ Wt) {
    __shared__ float t[64][65];
    int k0 = blockIdx.y * 64, d0 = blockIdx.x * 64;
    int c = threadIdx.x & 63, r4 = threadIdx.x >> 6;
    #pragma unroll
    for (int s = 0; s < 16; ++s) {
        int rr = r4 + s * 4;
        t[rr][c] = W[(size_t)(k0 + rr) * 512 + d0 + c];
    }
    __syncthreads();
    #pragma unroll
    for (int s = 0; s < 16; ++s) {
        int dd = r4 + s * 4;
        Wt[(size_t)(d0 + dd) * 512 + k0 + c] = (f16)(64.f * t[c][dd]);
    }
}

// X_h = f16(X0), flat
__global__ void k_cvtX(const float* __restrict__ x, f16* __restrict__ xh) {
    size_t i = ((size_t)blockIdx.x * 256 + threadIdx.x) * 4;
    float4 v = *(const float4*)(x + i);
    f16x4 o;
    o[0] = (f16)v.x; o[1] = (f16)v.y; o[2] = (f16)v.z; o[3] = (f16)v.w;
    *(f16x4*)(xh + i) = o;
}

// C[m][n] = sum_k P[m][k] * Qt[n][k];  out Ct[n][m] = act(C*iscale + bias[m]) * oscale
// M = N = K = 512, batched over blockIdx.z. m97 structure: 128x128 tile, 4 waves, BK=32.
template<bool BIAS, bool RELU, bool OUTF32>
__global__ __launch_bounds__(256)
void gemm_tn_ct(const f16* __restrict__ P, size_t pstr,
                const f16* __restrict__ Qt, size_t qstr,
                void* __restrict__ Cout, size_t cstr,
                const float* __restrict__ bias, float iscale, float oscale) {
    __shared__ __align__(16) f16 Plds[128 * 32];
    __shared__ __align__(16) f16 Qlds[128 * 32];

    const int tid  = threadIdx.x;
    const int lane = tid & 63;
    const int wid  = tid >> 6;
    const int wm = wid >> 1, wn = wid & 1;

    const int b  = blockIdx.z;
    const int n0 = blockIdx.x * 128;
    const int m0 = blockIdx.y * 128;

    const f16* Pb = P + (size_t)b * pstr;
    const f16* Qb = Qt + (size_t)b * qstr;

    // staging geometry: chunk = 16 rows (64 lanes x 16B); lane -> (row, k-seg)
    const int srow  = lane >> 2;        // 0..15
    const int ssegh = (lane & 3) * 8;   // half offset 0,8,16,24

    // fragment geometry
    const int fr  = lane & 15;
    const int fkh = (lane >> 4) * 8;

    f32x4 acc[4][4] = {};

    for (int ks = 0; ks < 16; ++ks) {
        const int k0 = ks * 32;
        const int c0 = wid * 2;
        {
            const f16* ps = Pb + (size_t)(m0 + c0 * 16 + srow) * 512 + k0 + ssegh;
            gload_lds16(ps,            &Plds[c0 * 512]);
            gload_lds16(ps + 16 * 512, &Plds[(c0 + 1) * 512]);
            const f16* qs = Qb + (size_t)(n0 + c0 * 16 + srow) * 512 + k0 + ssegh;
            gload_lds16(qs,            &Qlds[c0 * 512]);
            gload_lds16(qs + 16 * 512, &Qlds[(c0 + 1) * 512]);
        }
        __syncthreads();
        f16x8 af[4], bf[4];
        #pragma unroll
        for (int mi = 0; mi < 4; ++mi)
            af[mi] = *(const f16x8*)&Plds[(wm * 64 + mi * 16 + fr) * 32 + fkh];
        #pragma unroll
        for (int ni = 0; ni < 4; ++ni)
            bf[ni] = *(const f16x8*)&Qlds[(wn * 64 + ni * 16 + fr) * 32 + fkh];
        #pragma unroll
        for (int mi = 0; mi < 4; ++mi)
            #pragma unroll
            for (int ni = 0; ni < 4; ++ni)
                acc[mi][ni] = __builtin_amdgcn_mfma_f32_16x16x32_f16(
                    af[mi], bf[ni], acc[mi][ni], 0, 0, 0);
        __syncthreads();
    }

    // epilogue: Ct[n][m], frag: n = l&15 (col), m = (l>>4)*4 + reg (row)
    const int cmb = (lane >> 4) * 4;
    #pragma unroll
    for (int mi = 0; mi < 4; ++mi) {
        #pragma unroll
        for (int ni = 0; ni < 4; ++ni) {
            const int n = n0 + wn * 64 + ni * 16 + fr;
            const int m = m0 + wm * 64 + mi * 16 + cmb;
            float v[4];
            #pragma unroll
            for (int q = 0; q < 4; ++q) {
                float x = acc[mi][ni][q] * iscale;
                if (BIAS) x += bias[m + q];
                if (RELU) x = fmaxf(x, 0.f);
                v[q] = x * oscale;
            }
            if (OUTF32) {
                float* Cb = (float*)Cout + (size_t)b * cstr;
                f32x4 o; o[0] = v[0]; o[1] = v[1]; o[2] = v[2]; o[3] = v[3];
                *(f32x4*)&Cb[(size_t)n * 512 + m] = o;
            } else {
                f16* Cb = (f16*)Cout + (size_t)b * cstr;
                f16x4 o; o[0] = (f16)v[0]; o[1] = (f16)v[1]; o[2] = (f16)v[2]; o[3] = (f16)v[3];
                *(f16x4*)&Cb[(size_t)n * 512 + m] = o;
            }
        }
    }
}

extern "C" void kernel_launch(void* const* d_in, const int* in_sizes, int n_in,
                              void* d_out, int out_size, void* d_ws, size_t ws_size,
                              hipStream_t stream) {
    const float* X0  = (const float*)d_in[0];
    const float* adj = (const float*)d_in[1];
    const float* W1  = (const float*)d_in[2];
    const float* b1  = (const float*)d_in[3];
    const float* W2  = (const float*)d_in[4];
    const float* b2  = (const float*)d_in[5];
    const float* W3  = (const float*)d_in[6];
    const float* b3  = (const float*)d_in[7];

    uint8_t* ws = (uint8_t*)d_ws;
    float* rbuf = (float*)ws;                              // 64*512*4   = 128 KiB
    f16* Wt1 = (f16*)(ws + 131072);                        // 3 * 512KiB
    f16* Wt2 = Wt1 + NN;
    f16* Wt3 = Wt2 + NN;
    f16* A_h = (f16*)(ws + 131072 + (size_t)3 * NN * 2);   // 32 MiB
    f16* X_h = A_h + (size_t)NB * NN;                      // 32 MiB
    f16* S_t = X_h + (size_t)NB * NN;                      // 32 MiB

    k_colsum<<<dim3(128),      dim3(256), 0, stream>>>(adj, rbuf);
    k_makeA <<<dim3(8, 8, NB), dim3(256), 0, stream>>>(adj, rbuf, A_h);
    k_transW<<<dim3(8, 8),     dim3(256), 0, stream>>>(W1, Wt1);
    k_transW<<<dim3(8, 8),     dim3(256), 0, stream>>>(W2, Wt2);
    k_transW<<<dim3(8, 8),     dim3(256), 0, stream>>>(W3, Wt3);
    k_cvtX  <<<dim3(16384),    dim3(256), 0, stream>>>(X0, X_h);

    dim3 gg(4, 4, NB), gb(256);
    // scales: X stored x1 (layer1) / x256 (layer3 input); W stored x64; A stored x16.
    // Layer 1:  S1 = X0 @ W1          -> acc = 64*S1,    store S1        (o = 1/64)
    gemm_tn_ct<false, false, false><<<gg, gb, 0, stream>>>(X_h, (size_t)NN, Wt1, (size_t)0,  S_t, (size_t)NN, nullptr, 1.f, 1.f / 64.f);
    //           X1 = relu(A@S1 + b1) -> acc = 16*(A S1), store X1        (i = 1/16)
    gemm_tn_ct<true,  true,  false><<<gg, gb, 0, stream>>>(S_t, (size_t)NN, A_h, (size_t)NN, X_h, (size_t)NN, b1, 1.f / 16.f, 1.f);
    // Layer 2:  acc = 64*S2,  store 256*S2                               (o = 4)
    gemm_tn_ct<false, false, false><<<gg, gb, 0, stream>>>(X_h, (size_t)NN, Wt2, (size_t)0,  S_t, (size_t)NN, nullptr, 1.f, 4.f);
    //           acc = 4096*(A S2), X2 = relu(acc/4096 + b2), store 256*X2
    gemm_tn_ct<true,  true,  false><<<gg, gb, 0, stream>>>(S_t, (size_t)NN, A_h, (size_t)NN, X_h, (size_t)NN, b2, 1.f / 4096.f, 256.f);
    // Layer 3:  acc = 256*64*S3, store 256*S3                            (o = 1/64)
    gemm_tn_ct<false, false, false><<<gg, gb, 0, stream>>>(X_h, (size_t)NN, Wt3, (size_t)0,  S_t, (size_t)NN, nullptr, 1.f, 1.f / 64.f);
    //           acc = 4096*(A S3), out = acc/4096 + b3  (f32, no relu)
    gemm_tn_ct<true,  false, true ><<<gg, gb, 0, stream>>>(S_t, (size_t)NN, A_h, (size_t)NN, d_out, (size_t)NN, b3, 1.f / 4096.f, 1.f);
}

// Round 2
// 253.347 us; speedup vs baseline: 1.2393x; 1.2393x over previous
//
#include <hip/hip_runtime.h>
#include <cstdint>
#include <cstddef>

typedef _Float16 f16;
typedef _Float16 f16x4 __attribute__((ext_vector_type(4)));
typedef _Float16 f16x8 __attribute__((ext_vector_type(8)));
typedef float    f32x4 __attribute__((ext_vector_type(4)));

#define NB 64
#define NN 262144   // 512*512

__device__ __forceinline__ void gload_lds16(const void* g, void* l) {
    __builtin_amdgcn_global_load_lds(
        (const __attribute__((address_space(1))) void*)g,
        (__attribute__((address_space(3))) void*)l, 16, 0, 0);
}

// Stage A: part[b][ch][n] = sum of 32 rows of adj[b][:, n]
__global__ void k_colsum_part(const float* __restrict__ adj, float* __restrict__ part) {
    int b = blockIdx.y, ch = blockIdx.x;          // ch 0..15
    const float* ab = adj + (size_t)b * NN + (size_t)ch * 32 * 512;
    int c = threadIdx.x;                          // 0..255
    float s0 = 0.f, s1 = 0.f;
    #pragma unroll 8
    for (int i = 0; i < 32; ++i) {
        s0 += ab[i * 512 + c];
        s1 += ab[i * 512 + c + 256];
    }
    float* p = part + ((size_t)b * 16 + ch) * 512;
    p[c] = s0; p[c + 256] = s1;
}

// Stage B: r[b][n] = rsqrt(sum_ch part) with 0 -> 0
__global__ void k_colsum_fin(const float* __restrict__ part, float* __restrict__ r) {
    int idx = blockIdx.x * 256 + threadIdx.x;     // 0..32767
    int b = idx >> 9, n = idx & 511;
    const float* p = part + (size_t)b * 16 * 512 + n;
    float s = 0.f;
    #pragma unroll
    for (int ch = 0; ch < 16; ++ch) s += p[ch * 512];
    r[idx] = (s > 0.f) ? rsqrtf(s) : 0.f;
}

// A_h[b][i][j] = f16( 16 * r[b][i] * adj[b][j][i] * r[b][j] )   (tiled transpose)
__global__ void k_makeA(const float* __restrict__ adj, const float* __restrict__ r,
                        f16* __restrict__ A_h) {
    __shared__ float t[64][65];
    int b = blockIdx.z;
    int i0 = blockIdx.y * 64, j0 = blockIdx.x * 64;
    const float* ab = adj + (size_t)b * NN;
    int c = threadIdx.x & 63, r4 = threadIdx.x >> 6;
    #pragma unroll
    for (int s = 0; s < 16; ++s) {
        int rr = r4 + s * 4;
        t[rr][c] = ab[(size_t)(j0 + rr) * 512 + i0 + c];   // t[j][i] = adj[b][j0+j][i0+i]
    }
    __syncthreads();
    const float* rb = r + (size_t)b * 512;
    f16* Ab = A_h + (size_t)b * NN;
    int jq = (threadIdx.x & 15) * 4;   // j quad
    int ib = threadIdx.x >> 4;         // 0..15
    #pragma unroll
    for (int s = 0; s < 4; ++s) {
        int ii = ib + s * 16;
        float ri = 16.f * rb[i0 + ii];
        f16x4 o;
        #pragma unroll
        for (int q = 0; q < 4; ++q)
            o[q] = (f16)(ri * t[jq + q][ii] * rb[j0 + jq + q]);
        *(f16x4*)&Ab[(size_t)(i0 + ii) * 512 + j0 + jq] = o;
    }
}

// Wt[z][d][k] = f16( 64 * Wz[k][d] ), all three weights in one launch
__global__ void k_transW(const float* __restrict__ W1, const float* __restrict__ W2,
                         const float* __restrict__ W3, f16* __restrict__ Wt) {
    __shared__ float t[64][65];
    const float* W = blockIdx.z == 0 ? W1 : (blockIdx.z == 1 ? W2 : W3);
    f16* out = Wt + (size_t)blockIdx.z * NN;
    int k0 = blockIdx.y * 64, d0 = blockIdx.x * 64;
    int c = threadIdx.x & 63, r4 = threadIdx.x >> 6;
    #pragma unroll
    for (int s = 0; s < 16; ++s) {
        int rr = r4 + s * 4;
        t[rr][c] = W[(size_t)(k0 + rr) * 512 + d0 + c];    // t[k][d]
    }
    __syncthreads();
    int kq = (threadIdx.x & 15) * 4;
    int db = threadIdx.x >> 4;
    #pragma unroll
    for (int s = 0; s < 4; ++s) {
        int dd = db + s * 16;
        f16x4 o;
        #pragma unroll
        for (int q = 0; q < 4; ++q)
            o[q] = (f16)(64.f * t[kq + q][dd]);
        *(f16x4*)&out[(size_t)(d0 + dd) * 512 + k0 + kq] = o;
    }
}

// X_h = f16(X0), flat, 8 elems/lane
__global__ void k_cvtX(const float* __restrict__ x, f16* __restrict__ xh) {
    size_t i = ((size_t)blockIdx.x * 256 + threadIdx.x) * 8;
    float4 v0 = *(const float4*)(x + i);
    float4 v1 = *(const float4*)(x + i + 4);
    f16x8 o;
    o[0] = (f16)v0.x; o[1] = (f16)v0.y; o[2] = (f16)v0.z; o[3] = (f16)v0.w;
    o[4] = (f16)v1.x; o[5] = (f16)v1.y; o[6] = (f16)v1.z; o[7] = (f16)v1.w;
    *(f16x8*)(xh + i) = o;
}

// C[m][n] = sum_k P[m][k] * Qt[n][k];  out Ct[n][m] = act(C*iscale + bias[m]) * oscale
// M = N = K = 512, batch folded into 1D grid with XCD-contiguous swizzle.
template<bool BIAS, bool RELU, bool OUTF32>
__global__ __launch_bounds__(256)
void gemm_tn_ct(const f16* __restrict__ P, size_t pstr,
                const f16* __restrict__ Qt, size_t qstr,
                void* __restrict__ Cout, size_t cstr,
                const float* __restrict__ bias, float iscale, float oscale) {
    __shared__ __align__(16) f16 Plds[128 * 32];
    __shared__ __align__(16) f16 Qlds[128 * 32];

    const int tid  = threadIdx.x;
    const int lane = tid & 63;
    const int wid  = tid >> 6;
    const int wm = wid >> 1, wn = wid & 1;

    // XCD-contiguous swizzle: grid = 1024 WGs, 8 XCDs x 128 WGs = 8 batches/XCD
    const int wg  = blockIdx.x;
    const int swz = (wg & 7) * 128 + (wg >> 3);
    const int b   = swz >> 4;
    const int tt  = swz & 15;
    const int n0 = (tt & 3) * 128;
    const int m0 = (tt >> 2) * 128;

    const f16* Pb = P + (size_t)b * pstr;
    const f16* Qb = Qt + (size_t)b * qstr;

    // staging geometry: chunk = 16 rows (64 lanes x 16B); lane -> (row, k-seg)
    const int srow  = lane >> 2;        // 0..15
    const int ssegh = (lane & 3) * 8;   // elem offset 0,8,16,24

    // fragment geometry
    const int fr  = lane & 15;
    const int fkh = (lane >> 4) * 8;

    f32x4 acc[4][4] = {};

    for (int ks = 0; ks < 16; ++ks) {
        const int k0 = ks * 32;
        const int c0 = wid * 2;
        {
            const f16* ps = Pb + (size_t)(m0 + c0 * 16 + srow) * 512 + k0 + ssegh;
            gload_lds16(ps,            &Plds[c0 * 512]);
            gload_lds16(ps + 16 * 512, &Plds[(c0 + 1) * 512]);
            const f16* qs = Qb + (size_t)(n0 + c0 * 16 + srow) * 512 + k0 + ssegh;
            gload_lds16(qs,            &Qlds[c0 * 512]);
            gload_lds16(qs + 16 * 512, &Qlds[(c0 + 1) * 512]);
        }
        __syncthreads();
        f16x8 af[4], bf[4];
        #pragma unroll
        for (int mi = 0; mi < 4; ++mi)
            af[mi] = *(const f16x8*)&Plds[(wm * 64 + mi * 16 + fr) * 32 + fkh];
        #pragma unroll
        for (int ni = 0; ni < 4; ++ni)
            bf[ni] = *(const f16x8*)&Qlds[(wn * 64 + ni * 16 + fr) * 32 + fkh];
        #pragma unroll
        for (int mi = 0; mi < 4; ++mi)
            #pragma unroll
            for (int ni = 0; ni < 4; ++ni)
                acc[mi][ni] = __builtin_amdgcn_mfma_f32_16x16x32_f16(
                    af[mi], bf[ni], acc[mi][ni], 0, 0, 0);
        __syncthreads();
    }

    // epilogue: Ct[n][m], frag: n = l&15 (col), m = (l>>4)*4 + reg (row)
    const int cmb = (lane >> 4) * 4;
    #pragma unroll
    for (int mi = 0; mi < 4; ++mi) {
        #pragma unroll
        for (int ni = 0; ni < 4; ++ni) {
            const int n = n0 + wn * 64 + ni * 16 + fr;
            const int m = m0 + wm * 64 + mi * 16 + cmb;
            float v[4];
            #pragma unroll
            for (int q = 0; q < 4; ++q) {
                float x = acc[mi][ni][q] * iscale;
                if (BIAS) x += bias[m + q];
                if (RELU) x = fmaxf(x, 0.f);
                v[q] = x * oscale;
            }
            if (OUTF32) {
                float* Cb = (float*)Cout + (size_t)b * cstr;
                f32x4 o; o[0] = v[0]; o[1] = v[1]; o[2] = v[2]; o[3] = v[3];
                *(f32x4*)&Cb[(size_t)n * 512 + m] = o;
            } else {
                f16* Cb = (f16*)Cout + (size_t)b * cstr;
                f16x4 o; o[0] = (f16)v[0]; o[1] = (f16)v[1]; o[2] = (f16)v[2]; o[3] = (f16)v[3];
                *(f16x4*)&Cb[(size_t)n * 512 + m] = o;
            }
        }
    }
}

extern "C" void kernel_launch(void* const* d_in, const int* in_sizes, int n_in,
                              void* d_out, int out_size, void* d_ws, size_t ws_size,
                              hipStream_t stream) {
    const float* X0  = (const float*)d_in[0];
    const float* adj = (const float*)d_in[1];
    const float* W1  = (const float*)d_in[2];
    const float* b1  = (const float*)d_in[3];
    const float* W2  = (const float*)d_in[4];
    const float* b2  = (const float*)d_in[5];
    const float* W3  = (const float*)d_in[6];
    const float* b3  = (const float*)d_in[7];

    uint8_t* ws = (uint8_t*)d_ws;
    float* rbuf = (float*)ws;                              // 64*512*4   = 128 KiB
    f16* Wt1 = (f16*)(ws + 131072);                        // 3 * 512KiB contiguous
    f16* Wt2 = Wt1 + NN;
    f16* Wt3 = Wt2 + NN;
    f16* A_h = (f16*)(ws + 131072 + (size_t)3 * NN * 2);   // 32 MiB
    f16* X_h = A_h + (size_t)NB * NN;                      // 32 MiB
    f16* S_t = X_h + (size_t)NB * NN;                      // 32 MiB
    float* part = (float*)S_t;   // 64*16*512*4 = 2 MiB, aliased: S_t first written by GEMM1 (later)

    k_colsum_part<<<dim3(16, 64), dim3(256), 0, stream>>>(adj, part);
    k_colsum_fin <<<dim3(128),    dim3(256), 0, stream>>>(part, rbuf);
    k_makeA <<<dim3(8, 8, NB), dim3(256), 0, stream>>>(adj, rbuf, A_h);
    k_transW<<<dim3(8, 8, 3),  dim3(256), 0, stream>>>(W1, W2, W3, Wt1);
    k_cvtX  <<<dim3(8192),     dim3(256), 0, stream>>>(X0, X_h);

    dim3 gg(1024), gb(256);
    // scales: X stored x1 (layer1) / x256 (layer3 input); W stored x64; A stored x16.
    // Layer 1:  S1 = X0 @ W1          -> acc = 64*S1,    store S1        (o = 1/64)
    gemm_tn_ct<false, false, false><<<gg, gb, 0, stream>>>(X_h, (size_t)NN, Wt1, (size_t)0,  S_t, (size_t)NN, nullptr, 1.f, 1.f / 64.f);
    //           X1 = relu(A@S1 + b1) -> acc = 16*(A S1), store X1        (i = 1/16)
    gemm_tn_ct<true,  true,  false><<<gg, gb, 0, stream>>>(S_t, (size_t)NN, A_h, (size_t)NN, X_h, (size_t)NN, b1, 1.f / 16.f, 1.f);
    // Layer 2:  acc = 64*S2,  store 256*S2                               (o = 4)
    gemm_tn_ct<false, false, false><<<gg, gb, 0, stream>>>(X_h, (size_t)NN, Wt2, (size_t)0,  S_t, (size_t)NN, nullptr, 1.f, 4.f);
    //           acc = 4096*(A S2), X2 = relu(acc/4096 + b2), store 256*X2
    gemm_tn_ct<true,  true,  false><<<gg, gb, 0, stream>>>(S_t, (size_t)NN, A_h, (size_t)NN, X_h, (size_t)NN, b2, 1.f / 4096.f, 256.f);
    // Layer 3:  acc = 256*64*S3, store 256*S3                            (o = 1/64)
    gemm_tn_ct<false, false, false><<<gg, gb, 0, stream>>>(X_h, (size_t)NN, Wt3, (size_t)0,  S_t, (size_t)NN, nullptr, 1.f, 1.f / 64.f);
    //           acc = 4096*(A S3), out = acc/4096 + b3  (f32, no relu)
    gemm_tn_ct<true,  false, true ><<<gg, gb, 0, stream>>>(S_t, (size_t)NN, A_h, (size_t)NN, d_out, (size_t)NN, b3, 1.f / 4096.f, 1.f);
}

// Round 3
// 222.896 us; speedup vs baseline: 1.4086x; 1.1366x over previous
//
#include <hip/hip_runtime.h>
#include <cstdint>
#include <cstddef>

typedef _Float16 f16;
typedef _Float16 f16x4 __attribute__((ext_vector_type(4)));
typedef _Float16 f16x8 __attribute__((ext_vector_type(8)));
typedef float    f32x4 __attribute__((ext_vector_type(4)));

#define NB 64
#define NN 262144   // 512*512

__device__ __forceinline__ void gload_lds16(const void* g, void* l) {
    __builtin_amdgcn_global_load_lds(
        (const __attribute__((address_space(1))) void*)g,
        (__attribute__((address_space(3))) void*)l, 16, 0, 0);
}

// Stage A: part[b][ch][n] = sum of 32 rows of adj[b][:, n]
__global__ void k_colsum_part(const float* __restrict__ adj, float* __restrict__ part) {
    int b = blockIdx.y, ch = blockIdx.x;          // ch 0..15
    const float* ab = adj + (size_t)b * NN + (size_t)ch * 32 * 512;
    int c = threadIdx.x;                          // 0..255
    float s0 = 0.f, s1 = 0.f;
    #pragma unroll 8
    for (int i = 0; i < 32; ++i) {
        s0 += ab[i * 512 + c];
        s1 += ab[i * 512 + c + 256];
    }
    float* p = part + ((size_t)b * 16 + ch) * 512;
    p[c] = s0; p[c + 256] = s1;
}

// Stage B: r[b][n] = rsqrt(sum_ch part) with 0 -> 0
__global__ void k_colsum_fin(const float* __restrict__ part, float* __restrict__ r) {
    int idx = blockIdx.x * 256 + threadIdx.x;     // 0..32767
    int b = idx >> 9, n = idx & 511;
    const float* p = part + (size_t)b * 16 * 512 + n;
    float s = 0.f;
    #pragma unroll
    for (int ch = 0; ch < 16; ++ch) s += p[ch * 512];
    r[idx] = (s > 0.f) ? rsqrtf(s) : 0.f;
}

// A_h[b][i][j] = f16( 16 * r[b][i] * adj[b][j][i] * r[b][j] )   (tiled transpose)
__global__ void k_makeA(const float* __restrict__ adj, const float* __restrict__ r,
                        f16* __restrict__ A_h) {
    __shared__ float t[64][65];
    int b = blockIdx.z;
    int i0 = blockIdx.y * 64, j0 = blockIdx.x * 64;
    const float* ab = adj + (size_t)b * NN;
    int c = threadIdx.x & 63, r4 = threadIdx.x >> 6;
    #pragma unroll
    for (int s = 0; s < 16; ++s) {
        int rr = r4 + s * 4;
        t[rr][c] = ab[(size_t)(j0 + rr) * 512 + i0 + c];   // t[j][i]
    }
    __syncthreads();
    const float* rb = r + (size_t)b * 512;
    f16* Ab = A_h + (size_t)b * NN;
    int jq = (threadIdx.x & 15) * 4;
    int ib = threadIdx.x >> 4;
    #pragma unroll
    for (int s = 0; s < 4; ++s) {
        int ii = ib + s * 16;
        float ri = 16.f * rb[i0 + ii];
        f16x4 o;
        #pragma unroll
        for (int q = 0; q < 4; ++q)
            o[q] = (f16)(ri * t[jq + q][ii] * rb[j0 + jq + q]);
        *(f16x4*)&Ab[(size_t)(i0 + ii) * 512 + j0 + jq] = o;
    }
}

// Wt[z][d][k] = f16( 64 * Wz[k][d] ), all three weights in one launch
__global__ void k_transW(const float* __restrict__ W1, const float* __restrict__ W2,
                         const float* __restrict__ W3, f16* __restrict__ Wt) {
    __shared__ float t[64][65];
    const float* W = blockIdx.z == 0 ? W1 : (blockIdx.z == 1 ? W2 : W3);
    f16* out = Wt + (size_t)blockIdx.z * NN;
    int k0 = blockIdx.y * 64, d0 = blockIdx.x * 64;
    int c = threadIdx.x & 63, r4 = threadIdx.x >> 6;
    #pragma unroll
    for (int s = 0; s < 16; ++s) {
        int rr = r4 + s * 4;
        t[rr][c] = W[(size_t)(k0 + rr) * 512 + d0 + c];
    }
    __syncthreads();
    int kq = (threadIdx.x & 15) * 4;
    int db = threadIdx.x >> 4;
    #pragma unroll
    for (int s = 0; s < 4; ++s) {
        int dd = db + s * 16;
        f16x4 o;
        #pragma unroll
        for (int q = 0; q < 4; ++q)
            o[q] = (f16)(64.f * t[kq + q][dd]);
        *(f16x4*)&out[(size_t)(d0 + dd) * 512 + k0 + kq] = o;
    }
}

// X_h = f16(X0), flat, 8 elems/lane
__global__ void k_cvtX(const float* __restrict__ x, f16* __restrict__ xh) {
    size_t i = ((size_t)blockIdx.x * 256 + threadIdx.x) * 8;
    float4 v0 = *(const float4*)(x + i);
    float4 v1 = *(const float4*)(x + i + 4);
    f16x8 o;
    o[0] = (f16)v0.x; o[1] = (f16)v0.y; o[2] = (f16)v0.z; o[3] = (f16)v0.w;
    o[4] = (f16)v1.x; o[5] = (f16)v1.y; o[6] = (f16)v1.z; o[7] = (f16)v1.w;
    *(f16x8*)(xh + i) = o;
}

// C[m][n] = sum_k P[m][k] * Qt[n][k];  out Ct[n][m] = act(C*iscale + bias[m]) * oscale
// 256x256 tile, BK=64, 8 waves (2Mx4N), double-buffered LDS, counted vmcnt pipeline.
// LDS layout: [256 rows][8 slots of 16B], slot XOR-swizzled by (row&7) on BOTH the
// staging source address and the fragment read address (linear gload_lds dest).
template<bool BIAS, bool RELU, bool OUTF32>
__global__ __launch_bounds__(512, 1)
void gemm_tn_ct(const f16* __restrict__ P, size_t pstr,
                const f16* __restrict__ Qt, size_t qstr,
                void* __restrict__ Cout, size_t cstr,
                const float* __restrict__ bias, float iscale, float oscale) {
    __shared__ __align__(16) f16 Plds[2][16384];   // 2 x 256x64 f16 = 64 KiB
    __shared__ __align__(16) f16 Qlds[2][16384];   // 64 KiB

    const int tid  = threadIdx.x;
    const int lane = tid & 63;
    const int wid  = tid >> 6;          // 0..7
    const int wm   = wid >> 2;          // 0..1  -> M half (128 rows)
    const int wn   = wid & 3;           // 0..3  -> N quarter (64 cols)

    // XCD-contiguous swizzle: 256 WGs, 8 XCDs x 32 = 8 batches/XCD
    const int wg  = blockIdx.x;
    const int swz = (wg & 7) * 32 + (wg >> 3);
    const int b   = swz >> 2;
    const int tt  = swz & 3;
    const int m0  = (tt >> 1) * 256;
    const int n0  = (tt & 1) * 256;

    const f16* Pb = P + (size_t)b * pstr;
    const f16* Qb = Qt + (size_t)b * qstr;

    // staging geometry: 512 threads, row = 64 k-elems (8 slots of 8 elems)
    const int srow = tid >> 3;                      // 0..63
    const int sswz = (tid & 7) ^ (srow & 7);        // swizzled source slot

    // fragment geometry
    const int fr  = lane & 15;
    const int fs  = lane >> 4;          // base slot 0..3 (krep adds 4)
    const int fx  = fr & 7;             // read-side XOR

    auto stage = [&](const f16* __restrict__ Gb, int row0, f16* lds, int k0) {
        #pragma unroll
        for (int r = 0; r < 4; ++r) {
            const f16* src = Gb + (size_t)(row0 + r * 64 + srow) * 512 + k0 + sswz * 8;
            gload_lds16(src, lds + r * 4096 + tid * 8);
        }
    };

    f32x4 acc[8][4] = {};

    // prologue: stage tile 0 into buffer 0 (8 loads outstanding)
    stage(Pb, m0, &Plds[0][0], 0);
    stage(Qb, n0, &Qlds[0][0], 0);

    for (int t = 0; t < 8; ++t) {
        const int nb = t & 1;
        if (t < 7) {
            // prefetch tile t+1 into the other buffer (its last reader finished
            // at the end-of-tile barrier of t-1)
            stage(Pb, m0, &Plds[nb ^ 1][0], (t + 1) * 64);
            stage(Qb, n0, &Qlds[nb ^ 1][0], (t + 1) * 64);
            asm volatile("s_waitcnt vmcnt(8)" ::: "memory");   // tile t landed; t+1 in flight
        } else {
            asm volatile("s_waitcnt vmcnt(0)" ::: "memory");
        }
        __builtin_amdgcn_s_barrier();

        const f16* Pl = &Plds[nb][0];
        const f16* Ql = &Qlds[nb][0];
        #pragma unroll
        for (int krep = 0; krep < 2; ++krep) {
            const int s = fs + krep * 4;
            const int sp = (s ^ fx) * 8;
            f16x8 af[8], bf[4];
            #pragma unroll
            for (int mi = 0; mi < 8; ++mi)
                af[mi] = *(const f16x8*)&Pl[(wm * 128 + mi * 16 + fr) * 64 + sp];
            #pragma unroll
            for (int ni = 0; ni < 4; ++ni)
                bf[ni] = *(const f16x8*)&Ql[(wn * 64 + ni * 16 + fr) * 64 + sp];
            __builtin_amdgcn_s_setprio(1);
            #pragma unroll
            for (int mi = 0; mi < 8; ++mi)
                #pragma unroll
                for (int ni = 0; ni < 4; ++ni)
                    acc[mi][ni] = __builtin_amdgcn_mfma_f32_16x16x32_f16(
                        af[mi], bf[ni], acc[mi][ni], 0, 0, 0);
            __builtin_amdgcn_s_setprio(0);
        }
        // all LDS reads of this tile serviced before anyone re-stages this buffer
        asm volatile("s_waitcnt lgkmcnt(0)" ::: "memory");
        __builtin_amdgcn_sched_barrier(0);
        __builtin_amdgcn_s_barrier();
    }

    // epilogue: Ct[n][m], frag: n = lane&15 (col), m = (lane>>4)*4 + reg (row)
    const int cmb = (lane >> 4) * 4;
    #pragma unroll
    for (int mi = 0; mi < 8; ++mi) {
        #pragma unroll
        for (int ni = 0; ni < 4; ++ni) {
            const int n = n0 + wn * 64 + ni * 16 + fr;
            const int m = m0 + wm * 128 + mi * 16 + cmb;
            float v[4];
            #pragma unroll
            for (int q = 0; q < 4; ++q) {
                float x = acc[mi][ni][q] * iscale;
                if (BIAS) x += bias[m + q];
                if (RELU) x = fmaxf(x, 0.f);
                v[q] = x * oscale;
            }
            if (OUTF32) {
                float* Cb = (float*)Cout + (size_t)b * cstr;
                f32x4 o; o[0] = v[0]; o[1] = v[1]; o[2] = v[2]; o[3] = v[3];
                *(f32x4*)&Cb[(size_t)n * 512 + m] = o;
            } else {
                f16* Cb = (f16*)Cout + (size_t)b * cstr;
                f16x4 o; o[0] = (f16)v[0]; o[1] = (f16)v[1]; o[2] = (f16)v[2]; o[3] = (f16)v[3];
                *(f16x4*)&Cb[(size_t)n * 512 + m] = o;
            }
        }
    }
}

extern "C" void kernel_launch(void* const* d_in, const int* in_sizes, int n_in,
                              void* d_out, int out_size, void* d_ws, size_t ws_size,
                              hipStream_t stream) {
    const float* X0  = (const float*)d_in[0];
    const float* adj = (const float*)d_in[1];
    const float* W1  = (const float*)d_in[2];
    const float* b1  = (const float*)d_in[3];
    const float* W2  = (const float*)d_in[4];
    const float* b2  = (const float*)d_in[5];
    const float* W3  = (const float*)d_in[6];
    const float* b3  = (const float*)d_in[7];

    uint8_t* ws = (uint8_t*)d_ws;
    float* rbuf = (float*)ws;                              // 128 KiB
    f16* Wt1 = (f16*)(ws + 131072);                        // 3 x 512 KiB
    f16* Wt2 = Wt1 + NN;
    f16* Wt3 = Wt2 + NN;
    f16* A_h = (f16*)(ws + 131072 + (size_t)3 * NN * 2);   // 32 MiB
    f16* X_h = A_h + (size_t)NB * NN;                      // 32 MiB
    f16* S_t = X_h + (size_t)NB * NN;                      // 32 MiB
    float* part = (float*)S_t;   // 2 MiB, aliased: S_t first written later by GEMM1

    k_colsum_part<<<dim3(16, 64), dim3(256), 0, stream>>>(adj, part);
    k_colsum_fin <<<dim3(128),    dim3(256), 0, stream>>>(part, rbuf);
    k_makeA <<<dim3(8, 8, NB), dim3(256), 0, stream>>>(adj, rbuf, A_h);
    k_transW<<<dim3(8, 8, 3),  dim3(256), 0, stream>>>(W1, W2, W3, Wt1);
    k_cvtX  <<<dim3(8192),     dim3(256), 0, stream>>>(X0, X_h);

    dim3 gg(256), gb(512);
    // scales: X stored x1 (layer1) / x256 (layer3 input); W stored x64; A stored x16.
    gemm_tn_ct<false, false, false><<<gg, gb, 0, stream>>>(X_h, (size_t)NN, Wt1, (size_t)0,  S_t, (size_t)NN, nullptr, 1.f, 1.f / 64.f);
    gemm_tn_ct<true,  true,  false><<<gg, gb, 0, stream>>>(S_t, (size_t)NN, A_h, (size_t)NN, X_h, (size_t)NN, b1, 1.f / 16.f, 1.f);
    gemm_tn_ct<false, false, false><<<gg, gb, 0, stream>>>(X_h, (size_t)NN, Wt2, (size_t)0,  S_t, (size_t)NN, nullptr, 1.f, 4.f);
    gemm_tn_ct<true,  true,  false><<<gg, gb, 0, stream>>>(S_t, (size_t)NN, A_h, (size_t)NN, X_h, (size_t)NN, b2, 1.f / 4096.f, 256.f);
    gemm_tn_ct<false, false, false><<<gg, gb, 0, stream>>>(X_h, (size_t)NN, Wt3, (size_t)0,  S_t, (size_t)NN, nullptr, 1.f, 1.f / 64.f);
    gemm_tn_ct<true,  false, true ><<<gg, gb, 0, stream>>>(S_t, (size_t)NN, A_h, (size_t)NN, d_out, (size_t)NN, b3, 1.f / 4096.f, 1.f);
}